// Round 1
// baseline (382.040 us; speedup 1.0000x reference)
//
#include <hip/hip_runtime.h>
#include <math.h>

// Problem constants (fixed by reference)
constexpr int Bsz = 4;
constexpr int SEQ = 2048;
constexpr int DM  = 512;
constexpr int NH  = 8;
constexpr int HD  = 64;      // DM / NH
constexpr int LAG = 10;      // MAX_LAG
constexpr int MROWS = Bsz * SEQ;           // 8192
constexpr size_t OUT0_ELEMS = (size_t)Bsz * SEQ * DM;   // 4,194,304

// ---------------------------------------------------------------------------
// f32 tiled GEMM: C[M,N] = A[M,K] @ W[K,N] + bias[N]
// 64x64 tile, BK=16, 256 threads, 4x4 acc per thread.
// ---------------------------------------------------------------------------
constexpr int BM = 64, BN = 64, BK = 16;

__global__ __launch_bounds__(256) void gemm_bias_f32(
    const float* __restrict__ A, const float* __restrict__ W,
    const float* __restrict__ bias, float* __restrict__ C,
    int M, int N, int K) {
  __shared__ float As[BK][BM + 1];   // +1 pad: store-conflict reduction
  __shared__ float Ws[BK][BN];       // stride 64 keeps float4 reads aligned
  const int bm = blockIdx.y * BM;
  const int bn = blockIdx.x * BN;
  const int tid = threadIdx.x;
  const int tx = tid & 15;           // 0..15 -> N direction (x4)
  const int ty = tid >> 4;           // 0..15 -> M direction (x4)

  float acc[4][4] = {};

  for (int k0 = 0; k0 < K; k0 += BK) {
    // Load A tile: 64 rows x 16 k  (1024 elems, 4 per thread)
#pragma unroll
    for (int i = 0; i < 4; i++) {
      int idx = tid + i * 256;
      int r = idx >> 4, c = idx & 15;
      As[c][r] = A[(size_t)(bm + r) * K + (k0 + c)];
    }
    // Load W tile: 16 k x 64 cols (1024 elems, 4 per thread, coalesced 256B)
#pragma unroll
    for (int i = 0; i < 4; i++) {
      int idx = tid + i * 256;
      int r = idx >> 6, c = idx & 63;
      Ws[r][c] = W[(size_t)(k0 + r) * N + (bn + c)];
    }
    __syncthreads();

#pragma unroll
    for (int kk = 0; kk < BK; kk++) {
      float a0 = As[kk][ty * 4 + 0];
      float a1 = As[kk][ty * 4 + 1];
      float a2 = As[kk][ty * 4 + 2];
      float a3 = As[kk][ty * 4 + 3];
      float4 w4 = *(const float4*)&Ws[kk][tx * 4];
      acc[0][0] += a0 * w4.x; acc[0][1] += a0 * w4.y; acc[0][2] += a0 * w4.z; acc[0][3] += a0 * w4.w;
      acc[1][0] += a1 * w4.x; acc[1][1] += a1 * w4.y; acc[1][2] += a1 * w4.z; acc[1][3] += a1 * w4.w;
      acc[2][0] += a2 * w4.x; acc[2][1] += a2 * w4.y; acc[2][2] += a2 * w4.z; acc[2][3] += a2 * w4.w;
      acc[3][0] += a3 * w4.x; acc[3][1] += a3 * w4.y; acc[3][2] += a3 * w4.z; acc[3][3] += a3 * w4.w;
    }
    __syncthreads();
  }

  // Epilogue: add bias, float4 stores
  float4 b4 = *(const float4*)&bias[bn + tx * 4];
#pragma unroll
  for (int i = 0; i < 4; i++) {
    float4 o;
    o.x = acc[i][0] + b4.x;
    o.y = acc[i][1] + b4.y;
    o.z = acc[i][2] + b4.z;
    o.w = acc[i][3] + b4.w;
    *(float4*)&C[(size_t)(bm + ty * 4 + i) * N + (bn + tx * 4)] = o;
  }
}

// ---------------------------------------------------------------------------
// Banded causal attention.
// One block (256 threads) per (b, i) query row.
// Thread layout: h = tid>>5 (8 heads), lane = tid&31; each lane covers
// head-dims {lane, lane+32}.
// Band: j in [max(0, i-10), i], width <= 11. Off-band softmax terms are
// exactly 0 in f32 (expf(-1e9 - max) == 0), so band-only is exact.
// Writes ctx IN PLACE over q (block (b,i) is the only reader of q row i).
// Also writes attn_mean row (zeros + band values).
// ---------------------------------------------------------------------------
__global__ __launch_bounds__(256) void band_attn(
    const float* __restrict__ q, const float* __restrict__ k,
    const float* __restrict__ v, const float* __restrict__ decay_p,
    float* __restrict__ ctx, float* __restrict__ attn_out) {
  const int bi = blockIdx.x;          // 0 .. B*SEQ-1
  const int b = bi >> 11;             // / SEQ
  const int i = bi & (SEQ - 1);
  const int tid = threadIdx.x;
  const int h = tid >> 5;
  const int lane = tid & 31;

  __shared__ float dlds[LAG + 1];
  __shared__ float att_h[NH][LAG + 2];

  if (tid <= LAG) {
    float p = decay_p[tid];
    // stable softplus: max(p,0) + log1p(exp(-|p|))
    float sp = fmaxf(p, 0.0f) + log1pf(expf(-fabsf(p)));
    dlds[tid] = -logf(sp + 1e-8f);
  }
  __syncthreads();

  const int jlo = (i >= LAG) ? (i - LAG) : 0;
  const int nj = i - jlo + 1;

  const size_t rowq = ((size_t)(bi)*NH + h) * HD;
  const float q0 = q[rowq + lane];
  const float q1 = q[rowq + lane + 32];

  float s[LAG + 1];
#pragma unroll
  for (int jj = 0; jj <= LAG; jj++) {
    int j = jlo + jj;
    bool ok = (j <= i);
    int jc = ok ? j : i;  // clamp for safe load
    const size_t rowk = (((size_t)b * SEQ + jc) * NH + h) * HD;
    float part = q0 * k[rowk + lane] + q1 * k[rowk + lane + 32];
#pragma unroll
    for (int m = 16; m >= 1; m >>= 1) part += __shfl_xor(part, m, 32);
    s[jj] = ok ? (part * 0.125f + dlds[i - j]) : -1e30f;
  }

  // softmax over the band (registers only)
  float mx = -1e30f;
#pragma unroll
  for (int jj = 0; jj <= LAG; jj++) mx = fmaxf(mx, s[jj]);
  float sum = 0.0f;
#pragma unroll
  for (int jj = 0; jj <= LAG; jj++) { s[jj] = expf(s[jj] - mx); sum += s[jj]; }
  const float inv = 1.0f / sum;

  // ctx = sum_j p_j * v_j ; record per-head band probs
  float c0 = 0.0f, c1 = 0.0f;
#pragma unroll
  for (int jj = 0; jj <= LAG; jj++) {
    float p = s[jj] * inv;                 // 0 for invalid jj
    int jc = (jlo + jj <= i) ? (jlo + jj) : i;
    const size_t rowv = (((size_t)b * SEQ + jc) * NH + h) * HD;
    c0 += p * v[rowv + lane];
    c1 += p * v[rowv + lane + 32];
    if (lane == 0) att_h[h][jj] = p;
  }
  ctx[rowq + lane] = c0;
  ctx[rowq + lane + 32] = c1;
  __syncthreads();

  // attn_mean row: zero-fill then band write
  float* arow = attn_out + (size_t)bi * SEQ;
  float4* arow4 = (float4*)arow;
#pragma unroll
  for (int t = tid; t < SEQ / 4; t += 256)
    arow4[t] = make_float4(0.f, 0.f, 0.f, 0.f);
  __syncthreads();
  if (tid < nj) {
    float a = 0.0f;
#pragma unroll
    for (int hh = 0; hh < NH; hh++) a += att_h[hh][tid];
    arow[jlo + tid] = a * (1.0f / NH);
  }
}

// ---------------------------------------------------------------------------
extern "C" void kernel_launch(void* const* d_in, const int* in_sizes, int n_in,
                              void* d_out, int out_size, void* d_ws, size_t ws_size,
                              hipStream_t stream) {
  const float* x   = (const float*)d_in[0];
  const float* Wq  = (const float*)d_in[1];
  const float* bq  = (const float*)d_in[2];
  const float* Wk  = (const float*)d_in[3];
  const float* bk  = (const float*)d_in[4];
  const float* Wv  = (const float*)d_in[5];
  const float* bv  = (const float*)d_in[6];
  const float* Wo  = (const float*)d_in[7];
  const float* bo  = (const float*)d_in[8];
  const float* dec = (const float*)d_in[9];

  float* out      = (float*)d_out;                 // [B,S,D]
  float* attn_out = out + OUT0_ELEMS;              // [B,S,S]

  float* q = (float*)d_ws;                         // [B,S,D] (reused as ctx)
  float* kk = q + (size_t)MROWS * DM;
  float* vv = kk + (size_t)MROWS * DM;

  dim3 gg(DM / BN, MROWS / BM);  // (8, 128)
  dim3 tb(256);
  gemm_bias_f32<<<gg, tb, 0, stream>>>(x, Wq, bq, q,  MROWS, DM, DM);
  gemm_bias_f32<<<gg, tb, 0, stream>>>(x, Wk, bk, kk, MROWS, DM, DM);
  gemm_bias_f32<<<gg, tb, 0, stream>>>(x, Wv, bv, vv, MROWS, DM, DM);

  band_attn<<<MROWS, 256, 0, stream>>>(q, kk, vv, dec, q, attn_out);

  gemm_bias_f32<<<gg, tb, 0, stream>>>(q, Wo, bo, out, MROWS, DM, DM);
}

// Round 2
// 95.156 us; speedup vs baseline: 4.0149x; 4.0149x over previous
//
#include <hip/hip_runtime.h>
#include <hip/hip_bf16.h>
#include <math.h>

// Problem constants (fixed by reference)
constexpr int Bsz = 4;
constexpr int SEQ = 2048;
constexpr int DM  = 512;
constexpr int NH  = 8;
constexpr int HD  = 64;      // DM / NH
constexpr int LAG = 10;      // MAX_LAG
constexpr int MROWS = Bsz * SEQ;                        // 8192
constexpr size_t OUT0_ELEMS = (size_t)Bsz * SEQ * DM;   // 4,194,304
constexpr int NQKV = 3 * DM;                            // 1536

typedef __attribute__((ext_vector_type(8))) short short8;
typedef __attribute__((ext_vector_type(4))) float f32x4;

// ---------------------------------------------------------------------------
// async global -> LDS, 16B per lane. LDS dest is wave-uniform base + lane*16.
// ---------------------------------------------------------------------------
__device__ __forceinline__ void gload_lds16(const void* g, void* l) {
  __builtin_amdgcn_global_load_lds(
      (const __attribute__((address_space(1))) unsigned int*)g,
      (__attribute__((address_space(3))) unsigned int*)l, 16, 0, 0);
}

// ---------------------------------------------------------------------------
// Prep: f32 -> bf16 cast of x (vectorized, 8 elems/thread)
// ---------------------------------------------------------------------------
__global__ __launch_bounds__(256) void conv_x_bf16(
    const float* __restrict__ x, __hip_bfloat16* __restrict__ xb) {
  int i = (blockIdx.x * 256 + threadIdx.x) * 8;
  float4 a = *(const float4*)(x + i);
  float4 b = *(const float4*)(x + i + 4);
  union { __hip_bfloat16 h[8]; uint4 u; } pk;
  pk.h[0] = __float2bfloat16(a.x); pk.h[1] = __float2bfloat16(a.y);
  pk.h[2] = __float2bfloat16(a.z); pk.h[3] = __float2bfloat16(a.w);
  pk.h[4] = __float2bfloat16(b.x); pk.h[5] = __float2bfloat16(b.y);
  pk.h[6] = __float2bfloat16(b.z); pk.h[7] = __float2bfloat16(b.w);
  *(uint4*)(xb + i) = pk.u;
}

// ---------------------------------------------------------------------------
// Prep: transpose + cast weights. W [512][512] f32 (k-major rows) -> Wt [n][k] bf16.
// blockIdx.z selects {Wq,Wk,Wv,Wo}.
// ---------------------------------------------------------------------------
__global__ __launch_bounds__(256) void conv_w(
    const float* __restrict__ Wq, const float* __restrict__ Wk,
    const float* __restrict__ Wv, const float* __restrict__ Wo,
    __hip_bfloat16* __restrict__ Wtqkv, __hip_bfloat16* __restrict__ Wot) {
  const int z = blockIdx.z;
  const float* W = (z == 0) ? Wq : (z == 1) ? Wk : (z == 2) ? Wv : Wo;
  __hip_bfloat16* dst = (z < 3) ? (Wtqkv + (size_t)z * DM * DM) : Wot;
  __shared__ float t[32][33];
  const int n0 = blockIdx.x * 32, k0 = blockIdx.y * 32;
  const int tx = threadIdx.x & 31, ty = threadIdx.x >> 5;
#pragma unroll
  for (int r = 0; r < 4; r++)
    t[ty + r * 8][tx] = W[(size_t)(k0 + ty + r * 8) * DM + n0 + tx];
  __syncthreads();
#pragma unroll
  for (int r = 0; r < 4; r++)
    dst[(size_t)(n0 + ty + r * 8) * DM + k0 + tx] = __float2bfloat16(t[tx][ty + r * 8]);
}

__global__ __launch_bounds__(256) void bias_cat(
    const float* __restrict__ bq, const float* __restrict__ bk,
    const float* __restrict__ bv, float* __restrict__ bcat) {
  int i = blockIdx.x * 256 + threadIdx.x;
  if (i < NQKV)
    bcat[i] = (i < 512) ? bq[i] : (i < 1024) ? bk[i - 512] : bv[i - 1024];
}

// ---------------------------------------------------------------------------
// bf16 MFMA GEMM: C[M,N] = A[M,K] @ Bt[N,K]^T + bias[N]
// 128x128 tile, BK=64, 4 waves (2x2), each wave 64x64 = 4x4 frags of 16x16x32.
// m97 structure: global_load_lds(16B) staging, single LDS buffer, 2 barriers.
// XOR chunk swizzle (T2) applied via pre-swizzled global source + swizzled
// ds_read address (rule #21).
// ---------------------------------------------------------------------------
template <bool OUT_BF16>
__global__ __launch_bounds__(256) void gemm_mfma(
    const __hip_bfloat16* __restrict__ A, const __hip_bfloat16* __restrict__ Bt,
    const float* __restrict__ bias, void* __restrict__ Cout,
    int M, int N, int K) {
  __shared__ __align__(16) unsigned short As[128][64];
  __shared__ __align__(16) unsigned short Bs[128][64];
  const int tid = threadIdx.x;
  const int lane = tid & 63, wave = tid >> 6;
  const int wr = wave >> 1, wc = wave & 1;
  const int bm = blockIdx.y * 128, bn = blockIdx.x * 128;

  f32x4 acc[4][4];
#pragma unroll
  for (int mi = 0; mi < 4; mi++)
#pragma unroll
    for (int ni = 0; ni < 4; ni++) acc[mi][ni] = {0.f, 0.f, 0.f, 0.f};

  for (int k0 = 0; k0 < K; k0 += 64) {
    // Stage A tile: 128 rows x 64 k bf16 = 1024 x 16B granules, 4 per thread.
#pragma unroll
    for (int it = 0; it < 4; ++it) {
      const int g = it * 256 + tid;
      const int row = g >> 3, ch = g & 7;
      const int src_ch = ch ^ (row & 7);  // inverse swizzle on SOURCE
      gload_lds16(A + (size_t)(bm + row) * K + k0 + src_ch * 8,
                  (char*)As + (it * 256 + wave * 64) * 16);
    }
#pragma unroll
    for (int it = 0; it < 4; ++it) {
      const int g = it * 256 + tid;
      const int row = g >> 3, ch = g & 7;
      const int src_ch = ch ^ (row & 7);
      gload_lds16(Bt + (size_t)(bn + row) * K + k0 + src_ch * 8,
                  (char*)Bs + (it * 256 + wave * 64) * 16);
    }
    __syncthreads();   // compiler emits vmcnt(0) drain here (m97 behavior)

#pragma unroll
    for (int kk = 0; kk < 2; ++kk) {
      short8 a[4], b[4];
#pragma unroll
      for (int mi = 0; mi < 4; ++mi) {
        const int row = wr * 64 + mi * 16 + (lane & 15);
        const int ch = ((lane >> 4) + kk * 4) ^ (row & 7);  // swizzled read
        a[mi] = *(const short8*)((const char*)As + row * 128 + ch * 16);
      }
#pragma unroll
      for (int ni = 0; ni < 4; ++ni) {
        const int row = wc * 64 + ni * 16 + (lane & 15);
        const int ch = ((lane >> 4) + kk * 4) ^ (row & 7);
        b[ni] = *(const short8*)((const char*)Bs + row * 128 + ch * 16);
      }
#pragma unroll
      for (int mi = 0; mi < 4; ++mi)
#pragma unroll
        for (int ni = 0; ni < 4; ++ni)
          acc[mi][ni] = __builtin_amdgcn_mfma_f32_16x16x32_bf16(
              a[mi], b[ni], acc[mi][ni], 0, 0, 0);
    }
    __syncthreads();
  }

  // Epilogue. C/D layout (verified m89/m91): col = lane&15, row = (lane>>4)*4+reg.
  const int crow0 = bm + wr * 64 + (lane >> 4) * 4;
  const int ccol0 = bn + wc * 64 + (lane & 15);
#pragma unroll
  for (int ni = 0; ni < 4; ++ni) {
    const float bv = bias[ccol0 + ni * 16];
#pragma unroll
    for (int mi = 0; mi < 4; ++mi) {
#pragma unroll
      for (int r = 0; r < 4; ++r) {
        const float val = acc[mi][ni][r] + bv;
        const size_t off = (size_t)(crow0 + mi * 16 + r) * N + (ccol0 + ni * 16);
        if (OUT_BF16)
          ((__hip_bfloat16*)Cout)[off] = __float2bfloat16(val);
        else
          ((float*)Cout)[off] = val;
      }
    }
  }
}

// ---------------------------------------------------------------------------
// Banded causal attention (bandwidth LAG+1 = 11; off-band probs are exactly 0).
// One block per (b,i) row. qkv is bf16 [MROWS][1536] (q|k|v). ctx out bf16.
// ---------------------------------------------------------------------------
__global__ __launch_bounds__(256) void band_attn(
    const __hip_bfloat16* __restrict__ qkv, const float* __restrict__ decay_p,
    __hip_bfloat16* __restrict__ ctx, float* __restrict__ attn_out) {
  const int bi = blockIdx.x;
  const int b = bi >> 11;
  const int i = bi & (SEQ - 1);
  const int tid = threadIdx.x;
  const int h = tid >> 5;
  const int lane = tid & 31;

  __shared__ float dlds[LAG + 1];
  __shared__ float att_h[NH][LAG + 2];

  if (tid <= LAG) {
    float p = decay_p[tid];
    float sp = fmaxf(p, 0.0f) + log1pf(expf(-fabsf(p)));  // stable softplus
    dlds[tid] = -logf(sp + 1e-8f);
  }
  __syncthreads();

  const int jlo = (i >= LAG) ? (i - LAG) : 0;
  const int nj = i - jlo + 1;

  const __hip_bfloat16* qrow = qkv + (size_t)bi * NQKV + h * HD;
  const float q0 = __bfloat162float(qrow[lane]);
  const float q1 = __bfloat162float(qrow[lane + 32]);

  float s[LAG + 1];
#pragma unroll
  for (int jj = 0; jj <= LAG; jj++) {
    const int j = jlo + jj;
    const bool ok = (j <= i);
    const int jc = ok ? j : i;
    const __hip_bfloat16* krow =
        qkv + ((size_t)b * SEQ + jc) * NQKV + DM + h * HD;
    float part = q0 * __bfloat162float(krow[lane]) +
                 q1 * __bfloat162float(krow[lane + 32]);
#pragma unroll
    for (int m = 16; m >= 1; m >>= 1) part += __shfl_xor(part, m, 32);
    s[jj] = ok ? (part * 0.125f + dlds[i - j]) : -1e30f;
  }

  float mx = -1e30f;
#pragma unroll
  for (int jj = 0; jj <= LAG; jj++) mx = fmaxf(mx, s[jj]);
  float sum = 0.0f;
#pragma unroll
  for (int jj = 0; jj <= LAG; jj++) { s[jj] = expf(s[jj] - mx); sum += s[jj]; }
  const float inv = 1.0f / sum;

  float c0 = 0.0f, c1 = 0.0f;
#pragma unroll
  for (int jj = 0; jj <= LAG; jj++) {
    const float p = s[jj] * inv;
    const int jc = (jlo + jj <= i) ? (jlo + jj) : i;
    const __hip_bfloat16* vrow =
        qkv + ((size_t)b * SEQ + jc) * NQKV + 2 * DM + h * HD;
    c0 += p * __bfloat162float(vrow[lane]);
    c1 += p * __bfloat162float(vrow[lane + 32]);
    if (lane == 0) att_h[h][jj] = p;
  }
  ctx[(size_t)bi * DM + h * HD + lane] = __float2bfloat16(c0);
  ctx[(size_t)bi * DM + h * HD + lane + 32] = __float2bfloat16(c1);
  __syncthreads();

  // attn_mean row: zero-fill then band write
  float* arow = attn_out + (size_t)bi * SEQ;
  float4* arow4 = (float4*)arow;
#pragma unroll
  for (int t = tid; t < SEQ / 4; t += 256)
    arow4[t] = make_float4(0.f, 0.f, 0.f, 0.f);
  __syncthreads();
  if (tid < nj) {
    float a = 0.0f;
#pragma unroll
    for (int hh = 0; hh < NH; hh++) a += att_h[hh][tid];
    arow[jlo + tid] = a * (1.0f / NH);
  }
}

// ---------------------------------------------------------------------------
extern "C" void kernel_launch(void* const* d_in, const int* in_sizes, int n_in,
                              void* d_out, int out_size, void* d_ws, size_t ws_size,
                              hipStream_t stream) {
  const float* x   = (const float*)d_in[0];
  const float* Wq  = (const float*)d_in[1];
  const float* bq  = (const float*)d_in[2];
  const float* Wk  = (const float*)d_in[3];
  const float* bk  = (const float*)d_in[4];
  const float* Wv  = (const float*)d_in[5];
  const float* bv  = (const float*)d_in[6];
  const float* Wo  = (const float*)d_in[7];
  const float* bo  = (const float*)d_in[8];
  const float* dec = (const float*)d_in[9];

  float* out      = (float*)d_out;                 // [B,S,D]
  float* attn_out = out + OUT0_ELEMS;              // [B,S,S]

  // Workspace layout (all 16B-aligned): total ~44.05 MB
  char* w = (char*)d_ws;
  __hip_bfloat16* xb    = (__hip_bfloat16*)w;                 w += (size_t)MROWS * DM * 2;
  __hip_bfloat16* Wtqkv = (__hip_bfloat16*)w;                 w += (size_t)NQKV * DM * 2;
  __hip_bfloat16* Wot   = (__hip_bfloat16*)w;                 w += (size_t)DM * DM * 2;
  float*          bcat  = (float*)w;                          w += (size_t)NQKV * 4;
  __hip_bfloat16* qkv   = (__hip_bfloat16*)w;                 w += (size_t)MROWS * NQKV * 2;
  __hip_bfloat16* ctxb  = (__hip_bfloat16*)w;

  // Prep
  conv_x_bf16<<<MROWS * DM / (256 * 8), 256, 0, stream>>>(x, xb);
  conv_w<<<dim3(16, 16, 4), 256, 0, stream>>>(Wq, Wk, Wv, Wo, Wtqkv, Wot);
  bias_cat<<<6, 256, 0, stream>>>(bq, bk, bv, bcat);

  // Fused QKV projection: [8192,512] @ [512,1536] -> bf16 qkv
  gemm_mfma<true><<<dim3(NQKV / 128, MROWS / 128), 256, 0, stream>>>(
      xb, Wtqkv, bcat, qkv, MROWS, NQKV, DM);

  // Band attention
  band_attn<<<MROWS, 256, 0, stream>>>(qkv, dec, ctxb, attn_out);

  // Output projection: [8192,512] @ [512,512] -> f32 out
  gemm_mfma<false><<<dim3(DM / 128, MROWS / 128), 256, 0, stream>>>(
      ctxb, Wot, bo, out, MROWS, DM, DM);
}

// Round 3
// 83.483 us; speedup vs baseline: 4.5763x; 1.1398x over previous
//
#include <hip/hip_runtime.h>
#include <hip/hip_bf16.h>
#include <math.h>

// Problem constants (fixed by reference)
constexpr int Bsz = 4;
constexpr int SEQ = 2048;
constexpr int DM  = 512;
constexpr int NH  = 8;
constexpr int HD  = 64;      // DM / NH
constexpr int LAG = 10;      // MAX_LAG
constexpr int MROWS = Bsz * SEQ;                        // 8192
constexpr size_t OUT0_ELEMS = (size_t)Bsz * SEQ * DM;   // 4,194,304
constexpr int NQKV = 3 * DM;                            // 1536

typedef __attribute__((ext_vector_type(8))) short short8;
typedef __attribute__((ext_vector_type(4))) float f32x4;

__device__ __forceinline__ float bf2f(unsigned short u) {
  union { unsigned int i; float f; } x; x.i = (unsigned int)u << 16; return x.f;
}
__device__ __forceinline__ unsigned short f2bf(float f) {
  __hip_bfloat16 h = __float2bfloat16(f);
  return *(unsigned short*)&h;
}

// ---------------------------------------------------------------------------
// async global -> LDS, 16B per lane. LDS dest is wave-uniform base + lane*16.
// ---------------------------------------------------------------------------
__device__ __forceinline__ void gload_lds16(const void* g, void* l) {
  __builtin_amdgcn_global_load_lds(
      (const __attribute__((address_space(1))) unsigned int*)g,
      (__attribute__((address_space(3))) unsigned int*)l, 16, 0, 0);
}

// ---------------------------------------------------------------------------
// Fused prep: blocks [0,2048) cast x f32->bf16; [2048,3072) transpose+cast
// weights; block 3072 concatenates biases.
// ---------------------------------------------------------------------------
__global__ __launch_bounds__(256) void prep(
    const float* __restrict__ x, const float* __restrict__ Wq,
    const float* __restrict__ Wk, const float* __restrict__ Wv,
    const float* __restrict__ Wo, const float* __restrict__ bq,
    const float* __restrict__ bk, const float* __restrict__ bv,
    __hip_bfloat16* __restrict__ xb, __hip_bfloat16* __restrict__ Wtqkv,
    __hip_bfloat16* __restrict__ Wot, float* __restrict__ bcat) {
  __shared__ float t[32][33];
  const int blk = blockIdx.x;
  const int tid = threadIdx.x;
  if (blk < 2048) {
    // x cast, 8 elems/thread
    size_t i = ((size_t)blk * 256 + tid) * 8;
    float4 a = *(const float4*)(x + i);
    float4 b = *(const float4*)(x + i + 4);
    union { unsigned short h[8]; uint4 u; } pk;
    pk.h[0] = f2bf(a.x); pk.h[1] = f2bf(a.y); pk.h[2] = f2bf(a.z); pk.h[3] = f2bf(a.w);
    pk.h[4] = f2bf(b.x); pk.h[5] = f2bf(b.y); pk.h[6] = f2bf(b.z); pk.h[7] = f2bf(b.w);
    *(uint4*)(xb + i) = pk.u;
  } else if (blk < 3072) {
    const int zb = blk - 2048;
    const int z = zb >> 8, rem = zb & 255;
    const float* W = (z == 0) ? Wq : (z == 1) ? Wk : (z == 2) ? Wv : Wo;
    __hip_bfloat16* dst = (z < 3) ? (Wtqkv + (size_t)z * DM * DM) : Wot;
    const int n0 = (rem & 15) * 32, k0 = (rem >> 4) * 32;
    const int tx = tid & 31, ty = tid >> 5;
#pragma unroll
    for (int r = 0; r < 4; r++)
      t[ty + r * 8][tx] = W[(size_t)(k0 + ty + r * 8) * DM + n0 + tx];
    __syncthreads();
#pragma unroll
    for (int r = 0; r < 4; r++)
      dst[(size_t)(n0 + ty + r * 8) * DM + k0 + tx] =
          __float2bfloat16(t[tx][ty + r * 8]);
  } else {
    for (int i = tid; i < NQKV; i += 256)
      bcat[i] = (i < 512) ? bq[i] : (i < 1024) ? bk[i - 512] : bv[i - 1024];
  }
}

// ---------------------------------------------------------------------------
// bf16 MFMA GEMM: C[M,N] = A[M,K] @ Bt[N,K]^T + bias[N]
// 128x128 tile, BK=64, 4 waves (2x2), 16x16x32 MFMA, m97 structure.
// T2-style XOR swizzle via pre-swizzled SOURCE + swizzled ds_read (rule #21).
// T1 XCD-aware block swizzle (grid % 8 == 0).
// Epilogue staged through LDS (aliased over As/Bs) for coalesced stores.
// ---------------------------------------------------------------------------
template <bool OUT_BF16>
__global__ __launch_bounds__(256) void gemm_mfma(
    const __hip_bfloat16* __restrict__ A, const __hip_bfloat16* __restrict__ Bt,
    const float* __restrict__ bias, void* __restrict__ Cout,
    int N, int K, int gx) {
  __shared__ __align__(16) char smem[32768];
  unsigned short (*As)[64] = (unsigned short (*)[64])smem;            // [128][64]
  unsigned short (*Bs)[64] = (unsigned short (*)[64])(smem + 16384);  // [128][64]

  // XCD-aware bijective swizzle
  int lin = blockIdx.x;
  const int cpx = gridDim.x >> 3;
  lin = (lin & 7) * cpx + (lin >> 3);
  const int bm = (lin / gx) * 128;
  const int bn = (lin % gx) * 128;

  const int tid = threadIdx.x;
  const int lane = tid & 63, wave = tid >> 6;
  const int wr = wave >> 1, wc = wave & 1;

  f32x4 acc[4][4];
#pragma unroll
  for (int mi = 0; mi < 4; mi++)
#pragma unroll
    for (int ni = 0; ni < 4; ni++) acc[mi][ni] = {0.f, 0.f, 0.f, 0.f};

  for (int k0 = 0; k0 < K; k0 += 64) {
#pragma unroll
    for (int it = 0; it < 4; ++it) {
      const int g = it * 256 + tid;
      const int row = g >> 3, ch = g & 7;
      const int src_ch = ch ^ (row & 7);  // inverse swizzle on SOURCE
      gload_lds16(A + (size_t)(bm + row) * K + k0 + src_ch * 8,
                  (char*)As + (it * 256 + wave * 64) * 16);
    }
#pragma unroll
    for (int it = 0; it < 4; ++it) {
      const int g = it * 256 + tid;
      const int row = g >> 3, ch = g & 7;
      const int src_ch = ch ^ (row & 7);
      gload_lds16(Bt + (size_t)(bn + row) * K + k0 + src_ch * 8,
                  (char*)Bs + (it * 256 + wave * 64) * 16);
    }
    __syncthreads();

#pragma unroll
    for (int kk = 0; kk < 2; ++kk) {
      short8 a[4], b[4];
#pragma unroll
      for (int mi = 0; mi < 4; ++mi) {
        const int row = wr * 64 + mi * 16 + (lane & 15);
        const int ch = ((lane >> 4) + kk * 4) ^ (row & 7);  // swizzled read
        a[mi] = *(const short8*)((const char*)As + row * 128 + ch * 16);
      }
#pragma unroll
      for (int ni = 0; ni < 4; ++ni) {
        const int row = wc * 64 + ni * 16 + (lane & 15);
        const int ch = ((lane >> 4) + kk * 4) ^ (row & 7);
        b[ni] = *(const short8*)((const char*)Bs + row * 128 + ch * 16);
      }
#pragma unroll
      for (int mi = 0; mi < 4; ++mi)
#pragma unroll
        for (int ni = 0; ni < 4; ++ni)
          acc[mi][ni] = __builtin_amdgcn_mfma_f32_16x16x32_bf16(
              a[mi], b[ni], acc[mi][ni], 0, 0, 0);
    }
    __syncthreads();
  }

  // Epilogue staged through LDS (alias over As/Bs; safe after final barrier).
  // C/D layout: col = lane&15, row = (lane>>4)*4 + reg (m89/m91).
  if (OUT_BF16) {
    unsigned short (*Cs)[128] = (unsigned short (*)[128])smem;  // 32 KB
#pragma unroll
    for (int ni = 0; ni < 4; ++ni) {
      const float bv = bias[bn + wc * 64 + ni * 16 + (lane & 15)];
#pragma unroll
      for (int mi = 0; mi < 4; ++mi)
#pragma unroll
        for (int r = 0; r < 4; ++r) {
          const int row = wr * 64 + mi * 16 + (lane >> 4) * 4 + r;
          const int col = wc * 64 + ni * 16 + (lane & 15);
          Cs[row][col] = f2bf(acc[mi][ni][r] + bv);
        }
    }
    __syncthreads();
    __hip_bfloat16* C = (__hip_bfloat16*)Cout;
#pragma unroll
    for (int t = 0; t < 8; ++t) {
      const int g = t * 256 + tid;      // 2048 x 16B chunks
      const int row = g >> 4, ch = g & 15;
      *(uint4*)(C + (size_t)(bm + row) * N + bn + ch * 8) =
          *(const uint4*)&Cs[row][ch * 8];
    }
  } else {
    float (*Cs)[128] = (float (*)[128])smem;  // 32 KB = 64 rows
    float* C = (float*)Cout;
#pragma unroll
    for (int half = 0; half < 2; ++half) {
      if (wr == half) {
#pragma unroll
        for (int ni = 0; ni < 4; ++ni) {
          const float bv = bias[bn + wc * 64 + ni * 16 + (lane & 15)];
#pragma unroll
          for (int mi = 0; mi < 4; ++mi)
#pragma unroll
            for (int r = 0; r < 4; ++r) {
              const int row = mi * 16 + (lane >> 4) * 4 + r;  // 0..63
              const int col = wc * 64 + ni * 16 + (lane & 15);
              Cs[row][col] = acc[mi][ni][r] + bv;
            }
        }
      }
      __syncthreads();
#pragma unroll
      for (int t = 0; t < 8; ++t) {
        const int g = t * 256 + tid;    // 2048 x float4 chunks
        const int row = g >> 5, ch = g & 31;
        *(float4*)(C + (size_t)(bm + half * 64 + row) * N + bn + ch * 4) =
            *(const float4*)&Cs[row][ch * 4];
      }
      __syncthreads();
    }
  }
}

// ---------------------------------------------------------------------------
// Banded causal attention (band width LAG+1 = 11; off-band probs exactly 0).
// One block per (b,i) row; h = tid>>5, lane = tid&31; lane covers head-dims
// {2*lane, 2*lane+1} (bfloat162 vectorized).
// ---------------------------------------------------------------------------
__global__ __launch_bounds__(256) void band_attn(
    const __hip_bfloat16* __restrict__ qkv, const float* __restrict__ decay_p,
    __hip_bfloat16* __restrict__ ctx, float* __restrict__ attn_out) {
  const int bi = blockIdx.x;
  const int b = bi >> 11;
  const int i = bi & (SEQ - 1);
  const int tid = threadIdx.x;
  const int h = tid >> 5;
  const int lane = tid & 31;

  __shared__ float dlds[LAG + 1];
  __shared__ float att_h[NH][LAG + 2];

  if (tid <= LAG) {
    float p = decay_p[tid];
    float sp = fmaxf(p, 0.0f) + log1pf(expf(-fabsf(p)));  // stable softplus
    dlds[tid] = -logf(sp + 1e-8f);
  }
  __syncthreads();

  const int jlo = (i >= LAG) ? (i - LAG) : 0;
  const int nj = i - jlo + 1;

  const unsigned short* qrow =
      (const unsigned short*)(qkv + (size_t)bi * NQKV + h * HD) + 2 * lane;
  const unsigned int qu = *(const unsigned int*)qrow;
  const float q0 = bf2f((unsigned short)qu);
  const float q1 = bf2f((unsigned short)(qu >> 16));

  float s[LAG + 1];
#pragma unroll
  for (int jj = 0; jj <= LAG; jj++) {
    const int j = jlo + jj;
    const bool ok = (j <= i);
    const int jc = ok ? j : i;
    const unsigned int ku = *(const unsigned int*)(
        (const unsigned short*)(qkv + ((size_t)b * SEQ + jc) * NQKV + DM + h * HD) +
        2 * lane);
    float part = q0 * bf2f((unsigned short)ku) +
                 q1 * bf2f((unsigned short)(ku >> 16));
#pragma unroll
    for (int m = 16; m >= 1; m >>= 1) part += __shfl_xor(part, m, 32);
    s[jj] = ok ? (part * 0.125f + dlds[i - j]) : -1e30f;
  }

  float mx = -1e30f;
#pragma unroll
  for (int jj = 0; jj <= LAG; jj++) mx = fmaxf(mx, s[jj]);
  float sum = 0.0f;
#pragma unroll
  for (int jj = 0; jj <= LAG; jj++) { s[jj] = expf(s[jj] - mx); sum += s[jj]; }
  const float inv = 1.0f / sum;

  float c0 = 0.0f, c1 = 0.0f;
#pragma unroll
  for (int jj = 0; jj <= LAG; jj++) {
    const float p = s[jj] * inv;
    const int jc = (jlo + jj <= i) ? (jlo + jj) : i;
    const unsigned int vu = *(const unsigned int*)(
        (const unsigned short*)(qkv + ((size_t)b * SEQ + jc) * NQKV + 2 * DM + h * HD) +
        2 * lane);
    c0 += p * bf2f((unsigned short)vu);
    c1 += p * bf2f((unsigned short)(vu >> 16));
    if (lane == 0) att_h[h][jj] = p;
  }
  const unsigned int pk =
      ((unsigned int)f2bf(c1) << 16) | (unsigned int)f2bf(c0);
  *(unsigned int*)((unsigned short*)(ctx + (size_t)bi * DM + h * HD) + 2 * lane) = pk;
  __syncthreads();

  // attn_mean row: zero-fill then band write
  float* arow = attn_out + (size_t)bi * SEQ;
  float4* arow4 = (float4*)arow;
#pragma unroll
  for (int t = tid; t < SEQ / 4; t += 256)
    arow4[t] = make_float4(0.f, 0.f, 0.f, 0.f);
  __syncthreads();
  if (tid < nj) {
    float a = 0.0f;
#pragma unroll
    for (int hh = 0; hh < NH; hh++) a += att_h[hh][tid];
    arow[jlo + tid] = a * (1.0f / NH);
  }
}

// ---------------------------------------------------------------------------
extern "C" void kernel_launch(void* const* d_in, const int* in_sizes, int n_in,
                              void* d_out, int out_size, void* d_ws, size_t ws_size,
                              hipStream_t stream) {
  const float* x   = (const float*)d_in[0];
  const float* Wq  = (const float*)d_in[1];
  const float* bq  = (const float*)d_in[2];
  const float* Wk  = (const float*)d_in[3];
  const float* bk  = (const float*)d_in[4];
  const float* Wv  = (const float*)d_in[5];
  const float* bv  = (const float*)d_in[6];
  const float* Wo  = (const float*)d_in[7];
  const float* bo  = (const float*)d_in[8];
  const float* dec = (const float*)d_in[9];

  float* out      = (float*)d_out;                 // [B,S,D]
  float* attn_out = out + OUT0_ELEMS;              // [B,S,S]

  // Workspace layout (16B-aligned), ~44 MB
  char* w = (char*)d_ws;
  __hip_bfloat16* xb    = (__hip_bfloat16*)w;  w += (size_t)MROWS * DM * 2;
  __hip_bfloat16* Wtqkv = (__hip_bfloat16*)w;  w += (size_t)NQKV * DM * 2;
  __hip_bfloat16* Wot   = (__hip_bfloat16*)w;  w += (size_t)DM * DM * 2;
  float*          bcat  = (float*)w;           w += (size_t)NQKV * 4;
  __hip_bfloat16* qkv   = (__hip_bfloat16*)w;  w += (size_t)MROWS * NQKV * 2;
  __hip_bfloat16* ctxb  = (__hip_bfloat16*)w;

  prep<<<3073, 256, 0, stream>>>(x, Wq, Wk, Wv, Wo, bq, bk, bv,
                                 xb, Wtqkv, Wot, bcat);

  // Fused QKV projection: [8192,512] @ [512,1536] -> bf16 qkv
  gemm_mfma<true><<<768, 256, 0, stream>>>(xb, Wtqkv, bcat, qkv,
                                           NQKV, DM, NQKV / 128);

  band_attn<<<MROWS, 256, 0, stream>>>(qkv, dec, ctxb, attn_out);

  // Output projection: [8192,512] @ [512,512] -> f32 out
  gemm_mfma<false><<<256, 256, 0, stream>>>(ctxb, Wot, bo, out,
                                            DM, DM, DM / 128);
}

// Round 4
// 82.193 us; speedup vs baseline: 4.6481x; 1.0157x over previous
//
#include <hip/hip_runtime.h>
#include <hip/hip_bf16.h>
#include <math.h>

// Problem constants (fixed by reference)
constexpr int Bsz = 4;
constexpr int SEQ = 2048;
constexpr int DM  = 512;
constexpr int NH  = 8;
constexpr int HD  = 64;      // DM / NH
constexpr int LAG = 10;      // MAX_LAG
constexpr int MROWS = Bsz * SEQ;                        // 8192
constexpr size_t OUT0_ELEMS = (size_t)Bsz * SEQ * DM;   // 4,194,304
constexpr int NQKV = 3 * DM;                            // 1536

typedef __attribute__((ext_vector_type(8))) short short8;
typedef __attribute__((ext_vector_type(4))) float f32x4;
typedef __attribute__((ext_vector_type(16))) float f32x16;

__device__ __forceinline__ float bf2f(unsigned short u) {
  union { unsigned int i; float f; } x; x.i = (unsigned int)u << 16; return x.f;
}
__device__ __forceinline__ unsigned short f2bf(float f) {
  __hip_bfloat16 h = __float2bfloat16(f);
  return *(unsigned short*)&h;
}

// ---------------------------------------------------------------------------
// async global -> LDS, 16B per lane. LDS dest is wave-uniform base + lane*16.
// ---------------------------------------------------------------------------
__device__ __forceinline__ void gload_lds16(const void* g, void* l) {
  __builtin_amdgcn_global_load_lds(
      (const __attribute__((address_space(1))) unsigned int*)g,
      (__attribute__((address_space(3))) unsigned int*)l, 16, 0, 0);
}

// ---------------------------------------------------------------------------
// Fused prep: blocks [0,2048) cast x f32->bf16; [2048,3072) transpose+cast
// weights; block 3072 concatenates biases.
// ---------------------------------------------------------------------------
__global__ __launch_bounds__(256) void prep(
    const float* __restrict__ x, const float* __restrict__ Wq,
    const float* __restrict__ Wk, const float* __restrict__ Wv,
    const float* __restrict__ Wo, const float* __restrict__ bq,
    const float* __restrict__ bk, const float* __restrict__ bv,
    __hip_bfloat16* __restrict__ xb, __hip_bfloat16* __restrict__ Wtqkv,
    __hip_bfloat16* __restrict__ Wot, float* __restrict__ bcat) {
  __shared__ float t[32][33];
  const int blk = blockIdx.x;
  const int tid = threadIdx.x;
  if (blk < 2048) {
    // x cast, 8 elems/thread
    size_t i = ((size_t)blk * 256 + tid) * 8;
    float4 a = *(const float4*)(x + i);
    float4 b = *(const float4*)(x + i + 4);
    union { unsigned short h[8]; uint4 u; } pk;
    pk.h[0] = f2bf(a.x); pk.h[1] = f2bf(a.y); pk.h[2] = f2bf(a.z); pk.h[3] = f2bf(a.w);
    pk.h[4] = f2bf(b.x); pk.h[5] = f2bf(b.y); pk.h[6] = f2bf(b.z); pk.h[7] = f2bf(b.w);
    *(uint4*)(xb + i) = pk.u;
  } else if (blk < 3072) {
    const int zb = blk - 2048;
    const int z = zb >> 8, rem = zb & 255;
    const float* W = (z == 0) ? Wq : (z == 1) ? Wk : (z == 2) ? Wv : Wo;
    __hip_bfloat16* dst = (z < 3) ? (Wtqkv + (size_t)z * DM * DM) : Wot;
    const int n0 = (rem & 15) * 32, k0 = (rem >> 4) * 32;
    const int tx = tid & 31, ty = tid >> 5;
#pragma unroll
    for (int r = 0; r < 4; r++)
      t[ty + r * 8][tx] = W[(size_t)(k0 + ty + r * 8) * DM + n0 + tx];
    __syncthreads();
#pragma unroll
    for (int r = 0; r < 4; r++)
      dst[(size_t)(n0 + ty + r * 8) * DM + k0 + tx] =
          __float2bfloat16(t[tx][ty + r * 8]);
  } else {
    for (int i = tid; i < NQKV; i += 256)
      bcat[i] = (i < 512) ? bq[i] : (i < 1024) ? bk[i - 512] : bv[i - 1024];
  }
}

// ---------------------------------------------------------------------------
// bf16 MFMA GEMM: C[M,N] = A[M,K] @ Bt[N,K]^T + bias[N]
// 128x128 tile, BK=64, 4 waves (2x2), 32x32x16 MFMA (higher FLOP/cycle than
// 16x16x32 per m119, and half the MFMA instruction count per K-step).
// T2-style XOR swizzle via pre-swizzled SOURCE + swizzled ds_read (rule #21).
// T1 XCD-aware block swizzle (grid % 8 == 0).
// Epilogue staged through LDS (aliased over As/Bs) for coalesced stores.
//
// Fragment maps (gfx950, verified family):
//   A/B: lane l holds row/col = l&31, k = (l>>5)*8 + e  (e=0..7, 16B contig)
//   C/D: col = lane&31, row = (reg&3) + 8*(reg>>2) + 4*(lane>>5), reg=0..15
// ---------------------------------------------------------------------------
template <bool OUT_BF16>
__global__ __launch_bounds__(256) void gemm_mfma(
    const __hip_bfloat16* __restrict__ A, const __hip_bfloat16* __restrict__ Bt,
    const float* __restrict__ bias, void* __restrict__ Cout,
    int N, int K, int gx) {
  __shared__ __align__(16) char smem[32768];
  unsigned short (*As)[64] = (unsigned short (*)[64])smem;            // [128][64]
  unsigned short (*Bs)[64] = (unsigned short (*)[64])(smem + 16384);  // [128][64]

  // XCD-aware bijective swizzle
  int lin = blockIdx.x;
  const int cpx = gridDim.x >> 3;
  lin = (lin & 7) * cpx + (lin >> 3);
  const int bm = (lin / gx) * 128;
  const int bn = (lin % gx) * 128;

  const int tid = threadIdx.x;
  const int lane = tid & 63, wave = tid >> 6;
  const int wr = wave >> 1, wc = wave & 1;
  const int l31 = lane & 31, lhi = lane >> 5;

  f32x16 acc[2][2] = {};

  for (int k0 = 0; k0 < K; k0 += 64) {
#pragma unroll
    for (int it = 0; it < 4; ++it) {
      const int g = it * 256 + tid;
      const int row = g >> 3, ch = g & 7;
      const int src_ch = ch ^ (row & 7);  // inverse swizzle on SOURCE
      gload_lds16(A + (size_t)(bm + row) * K + k0 + src_ch * 8,
                  (char*)As + (it * 256 + wave * 64) * 16);
    }
#pragma unroll
    for (int it = 0; it < 4; ++it) {
      const int g = it * 256 + tid;
      const int row = g >> 3, ch = g & 7;
      const int src_ch = ch ^ (row & 7);
      gload_lds16(Bt + (size_t)(bn + row) * K + k0 + src_ch * 8,
                  (char*)Bs + (it * 256 + wave * 64) * 16);
    }
    __syncthreads();

#pragma unroll
    for (int kk = 0; kk < 4; ++kk) {   // 4 x K=16 sub-steps
      short8 a[2], b[2];
#pragma unroll
      for (int fi = 0; fi < 2; ++fi) {
        const int row = wr * 64 + fi * 32 + l31;
        const int ch = (kk * 2 + lhi) ^ (row & 7);  // swizzled read
        a[fi] = *(const short8*)((const char*)As + row * 128 + ch * 16);
      }
#pragma unroll
      for (int fj = 0; fj < 2; ++fj) {
        const int row = wc * 64 + fj * 32 + l31;
        const int ch = (kk * 2 + lhi) ^ (row & 7);
        b[fj] = *(const short8*)((const char*)Bs + row * 128 + ch * 16);
      }
#pragma unroll
      for (int fi = 0; fi < 2; ++fi)
#pragma unroll
        for (int fj = 0; fj < 2; ++fj)
          acc[fi][fj] = __builtin_amdgcn_mfma_f32_32x32x16_bf16(
              a[fi], b[fj], acc[fi][fj], 0, 0, 0);
    }
    __syncthreads();
  }

  // Epilogue staged through LDS (alias over As/Bs; safe after final barrier).
  if (OUT_BF16) {
    unsigned short (*Cs)[128] = (unsigned short (*)[128])smem;  // 32 KB
#pragma unroll
    for (int fj = 0; fj < 2; ++fj) {
      const float bv = bias[bn + wc * 64 + fj * 32 + l31];
      const int col = wc * 64 + fj * 32 + l31;
#pragma unroll
      for (int fi = 0; fi < 2; ++fi)
#pragma unroll
        for (int r = 0; r < 16; ++r) {
          const int row = wr * 64 + fi * 32 + (r & 3) + 8 * (r >> 2) + 4 * lhi;
          Cs[row][col] = f2bf(acc[fi][fj][r] + bv);
        }
    }
    __syncthreads();
    __hip_bfloat16* C = (__hip_bfloat16*)Cout;
#pragma unroll
    for (int t = 0; t < 8; ++t) {
      const int g = t * 256 + tid;      // 2048 x 16B chunks
      const int row = g >> 4, ch = g & 15;
      *(uint4*)(C + (size_t)(bm + row) * N + bn + ch * 8) =
          *(const uint4*)&Cs[row][ch * 8];
    }
  } else {
    float (*Cs)[128] = (float (*)[128])smem;  // 32 KB = 64 rows
    float* C = (float*)Cout;
#pragma unroll
    for (int half = 0; half < 2; ++half) {
      if (wr == half) {
#pragma unroll
        for (int fj = 0; fj < 2; ++fj) {
          const float bv = bias[bn + wc * 64 + fj * 32 + l31];
          const int col = wc * 64 + fj * 32 + l31;
#pragma unroll
          for (int fi = 0; fi < 2; ++fi)
#pragma unroll
            for (int r = 0; r < 16; ++r) {
              const int row = fi * 32 + (r & 3) + 8 * (r >> 2) + 4 * lhi;  // 0..63
              Cs[row][col] = acc[fi][fj][r] + bv;
            }
        }
      }
      __syncthreads();
#pragma unroll
      for (int t = 0; t < 8; ++t) {
        const int g = t * 256 + tid;    // 2048 x float4 chunks
        const int row = g >> 5, ch = g & 31;
        *(float4*)(C + (size_t)(bm + half * 64 + row) * N + bn + ch * 4) =
            *(const float4*)&Cs[row][ch * 4];
      }
      __syncthreads();
    }
  }
}

// ---------------------------------------------------------------------------
// Banded causal attention (band width LAG+1 = 11; off-band probs exactly 0).
// One block per (b,i) row; h = tid>>5, lane = tid&31; lane covers head-dims
// {2*lane, 2*lane+1} (bfloat162 vectorized).
// ---------------------------------------------------------------------------
__global__ __launch_bounds__(256) void band_attn(
    const __hip_bfloat16* __restrict__ qkv, const float* __restrict__ decay_p,
    __hip_bfloat16* __restrict__ ctx, float* __restrict__ attn_out) {
  const int bi = blockIdx.x;
  const int b = bi >> 11;
  const int i = bi & (SEQ - 1);
  const int tid = threadIdx.x;
  const int h = tid >> 5;
  const int lane = tid & 31;

  __shared__ float dlds[LAG + 1];
  __shared__ float att_h[NH][LAG + 2];

  if (tid <= LAG) {
    float p = decay_p[tid];
    float sp = fmaxf(p, 0.0f) + log1pf(expf(-fabsf(p)));  // stable softplus
    dlds[tid] = -logf(sp + 1e-8f);
  }
  __syncthreads();

  const int jlo = (i >= LAG) ? (i - LAG) : 0;
  const int nj = i - jlo + 1;

  const unsigned short* qrow =
      (const unsigned short*)(qkv + (size_t)bi * NQKV + h * HD) + 2 * lane;
  const unsigned int qu = *(const unsigned int*)qrow;
  const float q0 = bf2f((unsigned short)qu);
  const float q1 = bf2f((unsigned short)(qu >> 16));

  float s[LAG + 1];
#pragma unroll
  for (int jj = 0; jj <= LAG; jj++) {
    const int j = jlo + jj;
    const bool ok = (j <= i);
    const int jc = ok ? j : i;
    const unsigned int ku = *(const unsigned int*)(
        (const unsigned short*)(qkv + ((size_t)b * SEQ + jc) * NQKV + DM + h * HD) +
        2 * lane);
    float part = q0 * bf2f((unsigned short)ku) +
                 q1 * bf2f((unsigned short)(ku >> 16));
#pragma unroll
    for (int m = 16; m >= 1; m >>= 1) part += __shfl_xor(part, m, 32);
    s[jj] = ok ? (part * 0.125f + dlds[i - j]) : -1e30f;
  }

  float mx = -1e30f;
#pragma unroll
  for (int jj = 0; jj <= LAG; jj++) mx = fmaxf(mx, s[jj]);
  float sum = 0.0f;
#pragma unroll
  for (int jj = 0; jj <= LAG; jj++) { s[jj] = expf(s[jj] - mx); sum += s[jj]; }
  const float inv = 1.0f / sum;

  float c0 = 0.0f, c1 = 0.0f;
#pragma unroll
  for (int jj = 0; jj <= LAG; jj++) {
    const float p = s[jj] * inv;
    const int jc = (jlo + jj <= i) ? (jlo + jj) : i;
    const unsigned int vu = *(const unsigned int*)(
        (const unsigned short*)(qkv + ((size_t)b * SEQ + jc) * NQKV + 2 * DM + h * HD) +
        2 * lane);
    c0 += p * bf2f((unsigned short)vu);
    c1 += p * bf2f((unsigned short)(vu >> 16));
    if (lane == 0) att_h[h][jj] = p;
  }
  const unsigned int pk =
      ((unsigned int)f2bf(c1) << 16) | (unsigned int)f2bf(c0);
  *(unsigned int*)((unsigned short*)(ctx + (size_t)bi * DM + h * HD) + 2 * lane) = pk;
  __syncthreads();

  // attn_mean row: zero-fill then band write
  float* arow = attn_out + (size_t)bi * SEQ;
  float4* arow4 = (float4*)arow;
#pragma unroll
  for (int t = tid; t < SEQ / 4; t += 256)
    arow4[t] = make_float4(0.f, 0.f, 0.f, 0.f);
  __syncthreads();
  if (tid < nj) {
    float a = 0.0f;
#pragma unroll
    for (int hh = 0; hh < NH; hh++) a += att_h[hh][tid];
    arow[jlo + tid] = a * (1.0f / NH);
  }
}

// ---------------------------------------------------------------------------
extern "C" void kernel_launch(void* const* d_in, const int* in_sizes, int n_in,
                              void* d_out, int out_size, void* d_ws, size_t ws_size,
                              hipStream_t stream) {
  const float* x   = (const float*)d_in[0];
  const float* Wq  = (const float*)d_in[1];
  const float* bq  = (const float*)d_in[2];
  const float* Wk  = (const float*)d_in[3];
  const float* bk  = (const float*)d_in[4];
  const float* Wv  = (const float*)d_in[5];
  const float* bv  = (const float*)d_in[6];
  const float* Wo  = (const float*)d_in[7];
  const float* bo  = (const float*)d_in[8];
  const float* dec = (const float*)d_in[9];

  float* out      = (float*)d_out;                 // [B,S,D]
  float* attn_out = out + OUT0_ELEMS;              // [B,S,S]

  // Workspace layout (16B-aligned), ~44 MB
  char* w = (char*)d_ws;
  __hip_bfloat16* xb    = (__hip_bfloat16*)w;  w += (size_t)MROWS * DM * 2;
  __hip_bfloat16* Wtqkv = (__hip_bfloat16*)w;  w += (size_t)NQKV * DM * 2;
  __hip_bfloat16* Wot   = (__hip_bfloat16*)w;  w += (size_t)DM * DM * 2;
  float*          bcat  = (float*)w;           w += (size_t)NQKV * 4;
  __hip_bfloat16* qkv   = (__hip_bfloat16*)w;  w += (size_t)MROWS * NQKV * 2;
  __hip_bfloat16* ctxb  = (__hip_bfloat16*)w;

  prep<<<3073, 256, 0, stream>>>(x, Wq, Wk, Wv, Wo, bq, bk, bv,
                                 xb, Wtqkv, Wot, bcat);

  // Fused QKV projection: [8192,512] @ [512,1536] -> bf16 qkv
  gemm_mfma<true><<<768, 256, 0, stream>>>(xb, Wtqkv, bcat, qkv,
                                           NQKV, DM, NQKV / 128);

  band_attn<<<MROWS, 256, 0, stream>>>(qkv, dec, ctxb, attn_out);

  // Output projection: [8192,512] @ [512,512] -> f32 out
  gemm_mfma<false><<<256, 256, 0, stream>>>(ctxb, Wot, bo, out,
                                            DM, DM, DM / 128);
}